// Round 1
// baseline (1232.516 us; speedup 1.0000x reference)
//
#include <hip/hip_runtime.h>
#include <math.h>

#define NTHREADS 256

// Bilinear tap table entry, matching jax.image.resize(method='bilinear',
// antialias=False): sample_f = (o+0.5)*inv_scale - 0.5, triangle kernel,
// per-sample weight normalization (which reproduces edge clamping).
__device__ __forceinline__ void mk_tap(int o, float invs, int insz,
                                       int* i0, int* i1, float* w0, float* w1) {
    float fy = __fsub_rn(__fmul_rn(__fadd_rn((float)o, 0.5f), invs), 0.5f);
    float fl = floorf(fy);
    int y0 = (int)fl;
    float k0 = __fsub_rn(1.0f, fabsf(__fsub_rn(fy, fl)));
    float k1 = __fsub_rn(1.0f, fabsf(__fsub_rn(fy, __fadd_rn(fl, 1.0f))));
    bool v0 = (y0 >= 0);
    bool v1 = (y0 + 1 <= insz - 1);
    k0 = v0 ? k0 : 0.0f;
    k1 = v1 ? k1 : 0.0f;
    float ssum = __fadd_rn(k0, k1);
    *w0 = __fdiv_rn(k0, ssum);
    *w1 = __fdiv_rn(k1, ssum);
    *i0 = v0 ? y0 : 0;
    *i1 = v1 ? (y0 + 1) : (insz - 1);
}

__global__ void __launch_bounds__(NTHREADS)
var_tokenizer_kernel(const float* __restrict__ latents,
                     const float* __restrict__ w1g, const float* __restrict__ b1g,
                     const float* __restrict__ w2g, const float* __restrict__ b2g,
                     float* __restrict__ out) {
    // resolutions 1,2,4,6,8,10,12,16 ; token offsets 6*cumsum(hw)
    const int RESA[8] = {1, 2, 4, 6, 8, 10, 12, 16};
    const int OFF6[8] = {0, 6, 30, 126, 342, 726, 1326, 2190};

    __shared__ float f_l[6 * 256];       // residual latent 6x16x16
    __shared__ float r_pad[6 * 196];     // quantized codes, zero-padded 14x14/ch
    __shared__ float h_pad[48 * 196];    // hidden (post-GELU), zero-padded 14x14/ch
    __shared__ float z_l[6 * 144];       // conv2 output (unpadded)
    __shared__ int   dti0[16]; __shared__ int dti1[16];
    __shared__ float dtw0[16]; __shared__ float dtw1[16];
    __shared__ int   uti0[16]; __shared__ int uti1[16];
    __shared__ float utw0[16]; __shared__ float utw1[16];

    const int item = blockIdx.x;
    const int tid  = threadIdx.x;
    const int wv   = __builtin_amdgcn_readfirstlane(tid >> 6); // wave id (uniform)
    const int lane = tid & 63;

    const float* lat  = latents + (size_t)item * 1536;
    float*       outb = out + (size_t)item * 3726;

    for (int i = tid; i < 1536; i += NTHREADS) f_l[i] = lat[i];
    // One-time zero fill: since resolutions are monotonically increasing, every
    // border cell of every scale's (R+2)x(R+2) window is never written non-zero
    // before it is read at that scale.
    for (int i = tid; i < 6 * 196;  i += NTHREADS) r_pad[i] = 0.0f;
    for (int i = tid; i < 48 * 196; i += NTHREADS) h_pad[i] = 0.0f;

    // FSQ constants, replicating reference fp32 op order.
    const float HL8 = (8.0f - 1.0f) * (1.0f + 1.0e-3f) / 2.0f;  // 3.5035...
    const float HL5 = (5.0f - 1.0f) * (1.0f + 1.0e-3f) / 2.0f;  // 2.002...
    const float SH8 = (float)atanh((double)(0.5f / HL8));

    __syncthreads();

    for (int s = 0; s < 8; ++s) {
        const int R  = RESA[s];
        const int HW = R * R;
        const bool last = (s == 7);

        // --- per-scale bilinear tap tables (square, shared for rows/cols) ---
        if (tid < R) {
            float sc   = __fdiv_rn((float)R, 16.0f);   // out/in
            float invs = __fdiv_rn(1.0f, sc);
            mk_tap(tid, invs, 16, &dti0[tid], &dti1[tid], &dtw0[tid], &dtw1[tid]);
        } else if (tid >= 64 && tid < 80 && !last) {
            int o = tid - 64;
            float sc   = __fdiv_rn(16.0f, (float)R);
            float invs = __fdiv_rn(1.0f, sc);
            mk_tap(o, invs, R, &uti0[o], &uti1[o], &utw0[o], &utw1[o]);
        }
        __syncthreads();

        // --- S1: resize f -> (R,R), FSQ quantize, emit tokens (+ r_pad) ---
        const int off = OFF6[s];
        for (int t = tid; t < 6 * HW; t += NTHREADS) {
            int ox = t % R; int rest = t / R; int oy = rest % R; int c = rest / R;
            int y0 = dti0[oy], y1 = dti1[oy], x0 = dti0[ox], x1 = dti1[ox];
            float wy0 = dtw0[oy], wy1 = dtw1[oy], wx0 = dtw0[ox], wx1 = dtw1[ox];
            const float* fc = f_l + c * 256;
            float a00 = fc[y0 * 16 + x0], a01 = fc[y0 * 16 + x1];
            float a10 = fc[y1 * 16 + x0], a11 = fc[y1 * 16 + x1];
            // H-dim contraction first, then W (matches jax per-dim order)
            float t0 = __fadd_rn(__fmul_rn(wy0, a00), __fmul_rn(wy1, a10));
            float t1 = __fadd_rn(__fmul_rn(wy0, a01), __fmul_rn(wy1, a11));
            float v  = __fadd_rn(__fmul_rn(wx0, t0), __fmul_rn(wx1, t1));
            // FSQ (levels [8,8,8,5,5,5])
            bool is8 = (c < 3);
            float hl   = is8 ? HL8 : HL5;
            float offc = is8 ? 0.5f : 0.0f;
            float sh   = is8 ? SH8 : 0.0f;
            float arg  = __fadd_rn(v, sh);
            float th   = (float)tanh((double)arg);           // correctly-rounded f32
            float bounded = __fsub_rn(__fmul_rn(th, hl), offc);
            float q = __fmul_rn(rintf(bounded), is8 ? 0.25f : 0.5f); // exact /half_width
            outb[off + t] = q;
            if (!last) r_pad[c * 196 + (oy + 1) * 14 + (ox + 1)] = q;
        }
        if (last) break;
        __syncthreads();

        // --- S2: conv3x3 (6->48) + exact GELU; wave wv owns channels [12wv,12wv+12) ---
        const float* w1s = w1g + (size_t)s * 48 * 54;
        const float* b1s = b1g + (size_t)s * 48;
        for (int pb = 0; pb < HW; pb += 64) {
            int p = pb + lane;
            bool act = p < HW;
            int pc = act ? p : 0;
            int py = pc / R, px = pc - py * R;
            int pbase = py * 14 + px;          // top-left of 3x3 patch in padded coords
            float patch[6][9];
            #pragma unroll
            for (int ci = 0; ci < 6; ++ci) {
                const float* rp = r_pad + ci * 196 + pbase;
                #pragma unroll
                for (int dy = 0; dy < 3; ++dy) {
                    patch[ci][dy * 3 + 0] = rp[dy * 14 + 0];
                    patch[ci][dy * 3 + 1] = rp[dy * 14 + 1];
                    patch[ci][dy * 3 + 2] = rp[dy * 14 + 2];
                }
            }
            for (int kk = 0; kk < 12; ++kk) {
                int k = wv * 12 + kk;                  // wave-uniform -> s_load weights
                const float* wk = w1s + k * 54;
                float acc = 0.0f;
                #pragma unroll
                for (int ci = 0; ci < 6; ++ci)
                    #pragma unroll
                    for (int j = 0; j < 9; ++j)
                        acc = __fmaf_rn(wk[ci * 9 + j], patch[ci][j], acc);
                acc = __fadd_rn(acc, b1s[k]);
                // exact GELU: 0.5*x*(1+erf(x/sqrt(2)))
                float g = __fmul_rn(__fmul_rn(0.5f, acc),
                          __fadd_rn(1.0f, (float)erf((double)__fdiv_rn(acc, 1.41421356f))));
                if (act) h_pad[k * 196 + pbase + 15] = g;   // (py+1)*14 + (px+1)
            }
        }
        __syncthreads();

        // --- S3: conv3x3 (48->6); each thread: one position, all 6 out channels ---
        const float* w2s = w2g + (size_t)s * 6 * 432;
        const float* b2s = b2g + (size_t)s * 6;
        for (int pb = 0; pb < HW; pb += NTHREADS) {
            int p = pb + tid;
            bool act = p < HW;
            int pc = act ? p : 0;
            int py = pc / R, px = pc - py * R;
            int pbase = py * 14 + px;
            float acc[6] = {0.f, 0.f, 0.f, 0.f, 0.f, 0.f};
            for (int cb = 0; cb < 48; cb += 6) {
                float patch[6][9];
                #pragma unroll
                for (int ci = 0; ci < 6; ++ci) {
                    const float* hp = h_pad + (cb + ci) * 196 + pbase;
                    #pragma unroll
                    for (int dy = 0; dy < 3; ++dy) {
                        patch[ci][dy * 3 + 0] = hp[dy * 14 + 0];
                        patch[ci][dy * 3 + 1] = hp[dy * 14 + 1];
                        patch[ci][dy * 3 + 2] = hp[dy * 14 + 2];
                    }
                }
                #pragma unroll
                for (int ci = 0; ci < 6; ++ci)
                    #pragma unroll
                    for (int j = 0; j < 9; ++j) {
                        float v = patch[ci][j];
                        #pragma unroll
                        for (int co = 0; co < 6; ++co)
                            acc[co] = __fmaf_rn(w2s[(co * 48 + cb + ci) * 9 + j], v, acc[co]);
                    }
            }
            if (act) {
                #pragma unroll
                for (int co = 0; co < 6; ++co)
                    z_l[co * HW + p] = __fadd_rn(acc[co], b2s[co]);
            }
        }
        __syncthreads();

        // --- S4: f -= upsample(z, 16x16) ---
        for (int t = tid; t < 1536; t += NTHREADS) {
            int x = t & 15; int y = (t >> 4) & 15; int c = t >> 8;
            int y0 = uti0[y], y1 = uti1[y], x0 = uti0[x], x1 = uti1[x];
            float wy0 = utw0[y], wy1 = utw1[y], wx0 = utw0[x], wx1 = utw1[x];
            const float* zc = z_l + c * HW;
            float a00 = zc[y0 * R + x0], a01 = zc[y0 * R + x1];
            float a10 = zc[y1 * R + x0], a11 = zc[y1 * R + x1];
            float t0 = __fadd_rn(__fmul_rn(wy0, a00), __fmul_rn(wy1, a10));
            float t1 = __fadd_rn(__fmul_rn(wy0, a01), __fmul_rn(wy1, a11));
            float zv = __fadd_rn(__fmul_rn(wx0, t0), __fmul_rn(wx1, t1));
            f_l[t] = __fsub_rn(f_l[t], zv);
        }
        __syncthreads();
    }
}

extern "C" void kernel_launch(void* const* d_in, const int* in_sizes, int n_in,
                              void* d_out, int out_size, void* d_ws, size_t ws_size,
                              hipStream_t stream) {
    const float* latents = (const float*)d_in[0];
    const float* w1 = (const float*)d_in[1];
    const float* b1 = (const float*)d_in[2];
    const float* w2 = (const float*)d_in[3];
    const float* b2 = (const float*)d_in[4];
    float* out = (float*)d_out;
    int nitems = in_sizes[0] / 1536;   // B * 6*16*16
    var_tokenizer_kernel<<<nitems, NTHREADS, 0, stream>>>(latents, w1, b1, w2, b2, out);
}

// Round 2
// 821.503 us; speedup vs baseline: 1.5003x; 1.5003x over previous
//
#include <hip/hip_runtime.h>
#include <math.h>

#define NTHREADS 256

// Bilinear tap table entry, matching jax.image.resize(method='bilinear',
// antialias=False): sample_f = (o+0.5)*inv_scale - 0.5, triangle kernel,
// per-sample weight normalization (which reproduces edge clamping).
__device__ __forceinline__ void mk_tap(int o, float invs, int insz,
                                       int* i0, int* i1, float* w0, float* w1) {
    float fy = __fsub_rn(__fmul_rn(__fadd_rn((float)o, 0.5f), invs), 0.5f);
    float fl = floorf(fy);
    int y0 = (int)fl;
    float k0 = __fsub_rn(1.0f, fabsf(__fsub_rn(fy, fl)));
    float k1 = __fsub_rn(1.0f, fabsf(__fsub_rn(fy, __fadd_rn(fl, 1.0f))));
    bool v0 = (y0 >= 0);
    bool v1 = (y0 + 1 <= insz - 1);
    k0 = v0 ? k0 : 0.0f;
    k1 = v1 ? k1 : 0.0f;
    float ssum = __fadd_rn(k0, k1);
    *w0 = __fdiv_rn(k0, ssum);
    *w1 = __fdiv_rn(k1, ssum);
    *i0 = v0 ? y0 : 0;
    *i1 = v1 ? (y0 + 1) : (insz - 1);
}

__global__ void __launch_bounds__(NTHREADS)
var_tokenizer_kernel(const float* __restrict__ latents,
                     const float* __restrict__ w1g, const float* __restrict__ b1g,
                     const float* __restrict__ w2g, const float* __restrict__ b2g,
                     float* __restrict__ out) {
    const int RESA[8] = {1, 2, 4, 6, 8, 10, 12, 16};
    const int OFF6[8] = {0, 6, 30, 126, 342, 726, 1326, 2190};

    __shared__ float f_l[6 * 256];                   // residual latent 6x16x16
    __shared__ float r_pad[6 * 196];                 // codes, ch-major, zero-padded 14x14
    __shared__ __align__(16) float h_pm[196 * 48];   // hidden, POSITION-major, ring-padded
    __shared__ float z_l[6 * 144];                   // conv2 output (unpadded)
    __shared__ int   dti0[16]; __shared__ int dti1[16];
    __shared__ float dtw0[16]; __shared__ float dtw1[16];
    __shared__ int   uti0[16]; __shared__ int uti1[16];
    __shared__ float utw0[16]; __shared__ float utw1[16];

    const int item = blockIdx.x;
    const int tid  = threadIdx.x;
    const int wv   = __builtin_amdgcn_readfirstlane(tid >> 6); // wave id (uniform)
    const int lane = tid & 63;

    const float* lat  = latents + (size_t)item * 1536;
    float*       outb = out + (size_t)item * 3726;

    for (int i = tid; i < 1536; i += NTHREADS) f_l[i] = lat[i];
    // One-time zero fill: resolutions are monotonically increasing, so every
    // border cell of every scale's (R+2)x(R+2) window is never written non-zero
    // before it is read at that scale (smaller scales only write strictly
    // interior cells of larger windows).
    for (int i = tid; i < 6 * 196;  i += NTHREADS) r_pad[i] = 0.0f;
    for (int i = tid; i < 196 * 48; i += NTHREADS) h_pm[i] = 0.0f;

    // FSQ constants, replicating reference fp32 op order.
    const float HL8 = (8.0f - 1.0f) * (1.0f + 1.0e-3f) / 2.0f;  // 3.5035
    const float HL5 = (5.0f - 1.0f) * (1.0f + 1.0e-3f) / 2.0f;  // 2.002
    const float SH8 = (float)atanh((double)(0.5f / HL8));

    __syncthreads();

    for (int s = 0; s < 8; ++s) {
        const int R  = RESA[s];
        const int HW = R * R;
        const bool last = (s == 7);

        // --- per-scale bilinear tap tables (square, shared for rows/cols) ---
        if (tid < R) {
            float invs = __fdiv_rn(1.0f, __fdiv_rn((float)R, 16.0f));
            mk_tap(tid, invs, 16, &dti0[tid], &dti1[tid], &dtw0[tid], &dtw1[tid]);
        } else if (tid >= 64 && tid < 80 && !last) {
            int o = tid - 64;
            float invs = __fdiv_rn(1.0f, __fdiv_rn(16.0f, (float)R));
            mk_tap(o, invs, R, &uti0[o], &uti1[o], &utw0[o], &utw1[o]);
        }
        __syncthreads();

        // --- S1: resize f -> (R,R), FSQ quantize, emit tokens (+ r_pad) ---
        const int off = OFF6[s];
        for (int t = tid; t < 6 * HW; t += NTHREADS) {
            int ox = t % R; int rest = t / R; int oy = rest % R; int c = rest / R;
            int y0 = dti0[oy], y1 = dti1[oy], x0 = dti0[ox], x1 = dti1[ox];
            float wy0 = dtw0[oy], wy1 = dtw1[oy], wx0 = dtw0[ox], wx1 = dtw1[ox];
            const float* fc = f_l + c * 256;
            float a00 = fc[y0 * 16 + x0], a01 = fc[y0 * 16 + x1];
            float a10 = fc[y1 * 16 + x0], a11 = fc[y1 * 16 + x1];
            float t0 = __fadd_rn(__fmul_rn(wy0, a00), __fmul_rn(wy1, a10));
            float t1 = __fadd_rn(__fmul_rn(wy0, a01), __fmul_rn(wy1, a11));
            float v  = __fadd_rn(__fmul_rn(wx0, t0), __fmul_rn(wx1, t1));
            bool is8 = (c < 3);
            float hl   = is8 ? HL8 : HL5;
            float offc = is8 ? 0.5f : 0.0f;
            float sh   = is8 ? SH8 : 0.0f;
            float arg  = __fadd_rn(v, sh);
            float th   = (float)tanh((double)arg);  // boundary-critical: keep exact
            float bounded = __fsub_rn(__fmul_rn(th, hl), offc);
            float q = __fmul_rn(rintf(bounded), is8 ? 0.25f : 0.5f);
            outb[off + t] = q;
            if (!last) r_pad[c * 196 + (oy + 1) * 14 + (ox + 1)] = q;
        }
        if (last) break;
        __syncthreads();

        // --- S2: conv3x3 (6->48) + GELU; wave wv owns channels [12wv,12wv+12) ---
        const float* w1s = w1g + (size_t)s * 48 * 54;
        const float* b1s = b1g + (size_t)s * 48;
        for (int pb = 0; pb < HW; pb += 64) {
            int p = pb + lane;
            bool act = p < HW;
            int pc = act ? p : 0;
            int py = pc / R, px = pc - py * R;
            int pbase = py * 14 + px;          // top-left of 3x3 patch (padded coords)
            float patch[6][9];
            #pragma unroll
            for (int ci = 0; ci < 6; ++ci) {
                const float* rp = r_pad + ci * 196 + pbase;
                #pragma unroll
                for (int dy = 0; dy < 3; ++dy) {
                    patch[ci][dy * 3 + 0] = rp[dy * 14 + 0];
                    patch[ci][dy * 3 + 1] = rp[dy * 14 + 1];
                    patch[ci][dy * 3 + 2] = rp[dy * 14 + 2];
                }
            }
            for (int kk = 0; kk < 12; ++kk) {
                int k = wv * 12 + kk;                  // wave-uniform -> s_load weights
                const float* wk = w1s + k * 54;
                float acc = 0.0f;
                #pragma unroll
                for (int ci = 0; ci < 6; ++ci)
                    #pragma unroll
                    for (int j = 0; j < 9; ++j)
                        acc = __fmaf_rn(wk[ci * 9 + j], patch[ci][j], acc);
                acc = __fadd_rn(acc, b1s[k]);
                // exact GELU: 0.5*x*(1+erf(x/sqrt(2))); erff error is diluted
                // through the 432-term conv2 sum before any quantization boundary
                float g = __fmul_rn(__fmul_rn(0.5f, acc),
                          __fadd_rn(1.0f, erff(__fdiv_rn(acc, 1.41421356f))));
                if (act) h_pm[(pbase + 15) * 48 + k] = g;  // pixel (py+1,px+1)
            }
        }
        __syncthreads();

        // --- S3: conv3x3 (48->6), hidden read as b128 position-major ---
        const float* w2s = w2g + (size_t)s * 6 * 432;
        const float* b2s = b2g + (size_t)s * 6;
        {
            int p = tid;                 // HW <= 144 < 256: single round
            if (p < HW) {                // wave-level skip for dead waves
                int py = p / R, px = p - py * R;
                float acc[6];
                #pragma unroll
                for (int co = 0; co < 6; ++co) acc[co] = 0.0f;
                for (int dy = 0; dy < 3; ++dy) {
                    for (int dx = 0; dx < 3; ++dx) {
                        int q = (py + dy) * 14 + (px + dx);
                        const float* hp = h_pm + q * 48;
                        const float* wj = w2s + dy * 3 + dx;   // + j
                        #pragma unroll 2
                        for (int c4 = 0; c4 < 12; ++c4) {
                            float4 v = *(const float4*)(hp + c4 * 4);
                            const float* wc = wj + c4 * 36;    // (c4*4)*9
                            #pragma unroll
                            for (int co = 0; co < 6; ++co) {
                                acc[co] = __fmaf_rn(wc[(co * 48 + 0) * 9], v.x, acc[co]);
                                acc[co] = __fmaf_rn(wc[(co * 48 + 1) * 9], v.y, acc[co]);
                                acc[co] = __fmaf_rn(wc[(co * 48 + 2) * 9], v.z, acc[co]);
                                acc[co] = __fmaf_rn(wc[(co * 48 + 3) * 9], v.w, acc[co]);
                            }
                        }
                    }
                }
                #pragma unroll
                for (int co = 0; co < 6; ++co)
                    z_l[co * HW + p] = __fadd_rn(acc[co], b2s[co]);
            }
        }
        __syncthreads();

        // --- S4: f -= upsample(z, 16x16) ---
        for (int t = tid; t < 1536; t += NTHREADS) {
            int x = t & 15; int y = (t >> 4) & 15; int c = t >> 8;
            int y0 = uti0[y], y1 = uti1[y], x0 = uti0[x], x1 = uti1[x];
            float wy0 = utw0[y], wy1 = utw1[y], wx0 = utw0[x], wx1 = utw1[x];
            const float* zc = z_l + c * HW;
            float a00 = zc[y0 * R + x0], a01 = zc[y0 * R + x1];
            float a10 = zc[y1 * R + x0], a11 = zc[y1 * R + x1];
            float t0 = __fadd_rn(__fmul_rn(wy0, a00), __fmul_rn(wy1, a10));
            float t1 = __fadd_rn(__fmul_rn(wy0, a01), __fmul_rn(wy1, a11));
            float zv = __fadd_rn(__fmul_rn(wx0, t0), __fmul_rn(wx1, t1));
            f_l[t] = __fsub_rn(f_l[t], zv);
        }
        __syncthreads();
    }
}

extern "C" void kernel_launch(void* const* d_in, const int* in_sizes, int n_in,
                              void* d_out, int out_size, void* d_ws, size_t ws_size,
                              hipStream_t stream) {
    const float* latents = (const float*)d_in[0];
    const float* w1 = (const float*)d_in[1];
    const float* b1 = (const float*)d_in[2];
    const float* w2 = (const float*)d_in[3];
    const float* b2 = (const float*)d_in[4];
    float* out = (float*)d_out;
    int nitems = in_sizes[0] / 1536;   // B * 6*16*16
    var_tokenizer_kernel<<<nitems, NTHREADS, 0, stream>>>(latents, w1, b1, w2, b2, out);
}